// Round 7
// baseline (456.942 us; speedup 1.0000x reference)
//
#include <hip/hip_runtime.h>
#include <hip/hip_bf16.h>

#define T_DIM 512
#define L_DIM 128

typedef _Float16 h2 __attribute__((ext_vector_type(2)));

#if defined(__has_builtin)
#if __has_builtin(__builtin_amdgcn_fdot2)
#define HAS_FDOT2 1
#endif
#endif

__device__ __forceinline__ float fdot2_acc(h2 a, h2 b, float c) {
#ifdef HAS_FDOT2
    return __builtin_amdgcn_fdot2(a, b, c, false);
#else
    return c + (float)a.x * (float)b.x + (float)a.y * (float)b.y;
#endif
}

__device__ __forceinline__ h2 pack_f16(float a, float b) {
    return __builtin_bit_cast(h2, __builtin_amdgcn_cvt_pkrtz(a, b));
}

__device__ __forceinline__ h2 uint_as_h2(unsigned int v) {
    return __builtin_bit_cast(h2, v);
}

// LDS-only barrier: drains lgkmcnt but NOT vmcnt -> feats prefetch stays in
// flight across the step barrier.
__device__ __forceinline__ void lds_barrier() {
    asm volatile("s_waitcnt lgkmcnt(0)\n\ts_barrier" ::: "memory");
}

// TWO WAVES PER CHAIN (128 thr/block). Wave w's lane p owns the single
// label j = 2p + w -> its E column is 64 h2 = 64 VGPRs (i-pairs), so the
// full working set (~115 VGPRs) is register-resident — rounds 5/6 demanded
// 128 VGPRs for E alone and the compiler spilled it to scratch
// (VGPR_Count=108 < 128 was the proof), putting ~700 cyc of hidden reload
// latency on every step.
//
// Step: 16 broadcast ds_read_b128 pull all 128 u (f16) from LDS; 64 fdot2
// accumulate the full 128-i dot; u' = acc*exp(f) written back as one
// ds_write_b16; lgkm-only s_barrier. Multiplicative recurrence with
// u0-renorm every 16 steps (scale in S), one log at the end.
__global__ __launch_bounds__(128, 1) void crf_fwd_kernel(
    const float* __restrict__ feats,
    const float* __restrict__ transfer,
    const int* __restrict__ target,
    const int* __restrict__ startp,
    const int* __restrict__ stopp,
    float* __restrict__ out)
{
    __shared__ unsigned int LdsU[2][64] __attribute__((aligned(16)));
    __shared__ float LdsRed[8];

    const int tid  = threadIdx.x;
    const int lane = tid & 63;
    const int wv   = tid >> 6;              // 0 or 1
    const int j    = (lane << 1) | wv;      // label owned by this thread
    const int b    = blockIdx.x;
    const int start = startp[0];
    const int stop  = stopp[0];
    const float* fbase = feats + (size_t)b * T_DIM * L_DIM;
    const float LOG128 = 4.852030263919617f;

    // ---- one-time: this label's E column, Ehat = exp(transfer)/128 ----
    h2 E[64];
#pragma unroll
    for (int q = 0; q < 64; ++q) {
        float e0 = __expf(transfer[(2 * q)     * L_DIM + j]) * 0.0078125f;
        float e1 = __expf(transfer[(2 * q + 1) * L_DIM + j]) * 0.0078125f;
        E[q] = pack_f16(e0, e1);
    }
    const float trS = transfer[j * L_DIM + stop];

    // ---- init: u = exp(f_1 + tr[start] + f_2), one f16 per thread ----
    {
        float v2 = fbase[1 * L_DIM + j] + fbase[2 * L_DIM + j]
                 + transfer[start * L_DIM + j];
        reinterpret_cast<unsigned short*>(&LdsU[0][0])[j] =
            __builtin_bit_cast(unsigned short, (_Float16)__expf(v2));
    }
    // feats prefetch window: fa..fd hold f[t+1..t+4] at step t
    float fa  = fbase[3 * L_DIM + j];
    float fb_ = fbase[4 * L_DIM + j];
    float fc  = fbase[5 * L_DIM + j];
    float fd  = fbase[6 * L_DIM + j];
    float S = 0.f;
    lds_barrier();

    int cur = 0;
    float accF = 0.f;

#pragma unroll 4
    for (int t = 2; t <= T_DIM - 1; ++t) {
        int tp = t + 5; if (tp > T_DIM - 1) tp = T_DIM - 1;
        float fnew = fbase[tp * L_DIM + j];   // distance-4, never drained
        float fe = __expf(fa);

        const uint4* P4 = reinterpret_cast<const uint4*>(&LdsU[cur][0]);
        float a0 = 0.f, a1 = 0.f, a2 = 0.f, a3 = 0.f;
        bool renorm = ((t & 15) == 0);

#pragma unroll
        for (int g = 0; g < 4; ++g) {
            uint4 q0 = P4[4 * g + 0];
            uint4 q1 = P4[4 * g + 1];
            uint4 q2 = P4[4 * g + 2];
            uint4 q3 = P4[4 * g + 3];
            if (g == 0 && renorm) {           // u0 free from broadcast read
                float u0 = (float)uint_as_h2(q0.x).x;
                float rr = __builtin_amdgcn_rcpf(u0);
                S += __logf(u0);
                fe *= rr;
            }
            int e = g << 4;
            a0 = fdot2_acc(uint_as_h2(q0.x), E[e + 0],  a0);
            a1 = fdot2_acc(uint_as_h2(q0.y), E[e + 1],  a1);
            a2 = fdot2_acc(uint_as_h2(q0.z), E[e + 2],  a2);
            a3 = fdot2_acc(uint_as_h2(q0.w), E[e + 3],  a3);
            a0 = fdot2_acc(uint_as_h2(q1.x), E[e + 4],  a0);
            a1 = fdot2_acc(uint_as_h2(q1.y), E[e + 5],  a1);
            a2 = fdot2_acc(uint_as_h2(q1.z), E[e + 6],  a2);
            a3 = fdot2_acc(uint_as_h2(q1.w), E[e + 7],  a3);
            a0 = fdot2_acc(uint_as_h2(q2.x), E[e + 8],  a0);
            a1 = fdot2_acc(uint_as_h2(q2.y), E[e + 9],  a1);
            a2 = fdot2_acc(uint_as_h2(q2.z), E[e + 10], a2);
            a3 = fdot2_acc(uint_as_h2(q2.w), E[e + 11], a3);
            a0 = fdot2_acc(uint_as_h2(q3.x), E[e + 12], a0);
            a1 = fdot2_acc(uint_as_h2(q3.y), E[e + 13], a1);
            a2 = fdot2_acc(uint_as_h2(q3.z), E[e + 14], a2);
            a3 = fdot2_acc(uint_as_h2(q3.w), E[e + 15], a3);
        }
        float acc = (a0 + a1) + (a2 + a3);

        if (t < T_DIM - 1) {
            float un = acc * fe;
            fa = fb_; fb_ = fc; fc = fd; fd = fnew;   // renamed under unroll
            reinterpret_cast<unsigned short*>(&LdsU[cur ^ 1][0])[j] =
                __builtin_bit_cast(unsigned short, (_Float16)un);
            lds_barrier();
            cur ^= 1;
        } else {
            accF = acc;
        }
    }

    S += 510.0f * LOG128;   // folded 1/128 per dot

    // ---- sentence_score: LSE over this wave's 64 labels, then combine ----
    float x  = __logf(accF) + S + trS;
    float mx = x;
#pragma unroll
    for (int d = 1; d < 64; d <<= 1) mx = fmaxf(mx, __shfl_xor(mx, d));
    float ex = __expf(x - mx);
#pragma unroll
    for (int d = 1; d < 64; d <<= 1) ex += __shfl_xor(ex, d);

    // ---- gold score: 511 terms over 128 threads ----
    float es = 0.f, ts = 0.f;
#pragma unroll
    for (int k = 0; k < 4; ++k) {
        int t = 1 + tid + (k << 7);
        if (t < T_DIM) {
            int tg = target[b * T_DIM + t];
            es += fbase[t * L_DIM + tg];
            int pr = (t == 1) ? start : target[b * T_DIM + t - 1];
            ts += transfer[pr * L_DIM + tg];
        }
    }
#pragma unroll
    for (int d = 1; d < 64; d <<= 1) {
        es += __shfl_xor(es, d);
        ts += __shfl_xor(ts, d);
    }

    if (lane == 0) {
        LdsRed[wv] = mx; LdsRed[2 + wv] = ex;
        LdsRed[4 + wv] = es; LdsRed[6 + wv] = ts;
    }
    __syncthreads();

    if (tid == 0) {
        float M  = fmaxf(LdsRed[0], LdsRed[1]);
        float Sm = LdsRed[2] * __expf(LdsRed[0] - M)
                 + LdsRed[3] * __expf(LdsRed[1] - M);
        float sentence = M + __logf(Sm);
        float emit0 = fbase[start];          // feats[b, 0, start]
        out[b] = sentence - __expf(emit0 + LdsRed[4] + LdsRed[5]
                                         + LdsRed[6] + LdsRed[7]);
    }
}

extern "C" void kernel_launch(void* const* d_in, const int* in_sizes, int n_in,
                              void* d_out, int out_size, void* d_ws, size_t ws_size,
                              hipStream_t stream) {
    const float* feats    = (const float*)d_in[0];
    const float* transfer = (const float*)d_in[1];
    const int*   target   = (const int*)d_in[2];
    const int*   startp   = (const int*)d_in[3];
    const int*   stopp    = (const int*)d_in[4];
    float* outp = (float*)d_out;
    int B = in_sizes[0] / (T_DIM * L_DIM);
    hipLaunchKernelGGL(crf_fwd_kernel, dim3(B), dim3(128), 0, stream,
                       feats, transfer, target, startp, stopp, outp);
}

// Round 8
// 406.131 us; speedup vs baseline: 1.1251x; 1.1251x over previous
//
#include <hip/hip_runtime.h>
#include <hip/hip_bf16.h>

#define T_DIM 512
#define L_DIM 128

typedef _Float16 h2 __attribute__((ext_vector_type(2)));

#if defined(__has_builtin)
#if __has_builtin(__builtin_amdgcn_fdot2)
#define HAS_FDOT2 1
#endif
#endif

__device__ __forceinline__ float fdot2_acc(h2 a, h2 b, float c) {
#ifdef HAS_FDOT2
    return __builtin_amdgcn_fdot2(a, b, c, false);
#else
    return c + (float)a.x * (float)b.x + (float)a.y * (float)b.y;
#endif
}

__device__ __forceinline__ h2 pack_f16(float a, float b) {
    return __builtin_bit_cast(h2, __builtin_amdgcn_cvt_pkrtz(a, b));
}

__device__ __forceinline__ h2 uint_as_h2(unsigned int v) {
    return __builtin_bit_cast(h2, v);
}

// X-macro over i-pair index q = 0..63
#define FOR_Q(X) \
  X(0) X(1) X(2) X(3) X(4) X(5) X(6) X(7) \
  X(8) X(9) X(10) X(11) X(12) X(13) X(14) X(15) \
  X(16) X(17) X(18) X(19) X(20) X(21) X(22) X(23) \
  X(24) X(25) X(26) X(27) X(28) X(29) X(30) X(31) \
  X(32) X(33) X(34) X(35) X(36) X(37) X(38) X(39) \
  X(40) X(41) X(42) X(43) X(44) X(45) X(46) X(47) \
  X(48) X(49) X(50) X(51) X(52) X(53) X(54) X(55) \
  X(56) X(57) X(58) X(59) X(60) X(61) X(62) X(63)

// ONE WAVE PER CHAIN, E as 128 *named* h2 variables.
// Rounds 5-7 post-mortem: any E declared as an array (h2 E[64]/E0[64]) was
// never promoted to registers (VGPR_Count 68/108 < E size) and was re-read
// from scratch every step (~1000 cyc hidden latency). Named scalars have no
// alloca -> they can only leave registers via true regalloc spill, and peak
// pressure (~180) is under the 256 cap.
//
// Lane p owns labels 2p, 2p+1. Per step: 16 broadcast ds_read_b128 pull u
// (128 f16) from the 256 B double-buffered LDS image, consumed in 4 fenced
// groups (limits live u to 16 dwords); 128 fdot2; u' = acc*exp(f) written
// back as one ds_write_b32. Wave lockstep + s_waitcnt lgkmcnt(0) -> no
// s_barrier, and vmcnt is never drained so feats prefetch stays in flight.
__global__ __launch_bounds__(64, 1) void crf_fwd_kernel(
    const float* __restrict__ feats,
    const float* __restrict__ transfer,
    const int* __restrict__ target,
    const int* __restrict__ startp,
    const int* __restrict__ stopp,
    float* __restrict__ out)
{
    __shared__ unsigned int LdsU[2][64] __attribute__((aligned(16)));

    const int lane = threadIdx.x;       // owns label pair (2p, 2p+1)
    const int p    = lane;
    const int j0   = p << 1;
    const int b    = blockIdx.x;
    const int start = startp[0];
    const int stop  = stopp[0];
    const float* fbase = feats + (size_t)b * T_DIM * L_DIM;
    const float2* f2 = reinterpret_cast<const float2*>(fbase);
    const float LOG128 = 4.852030263919617f;

    // ---- E as named registers: Ehat = exp(transfer)/128 ----
#define DECL_E(q) h2 E0_##q, E1_##q;
    FOR_Q(DECL_E)
#undef DECL_E
#define INIT_E(q) { \
        const float2* r0_ = reinterpret_cast<const float2*>(transfer + (2*(q))   * L_DIM + j0); \
        const float2* r1_ = reinterpret_cast<const float2*>(transfer + (2*(q)+1) * L_DIM + j0); \
        float2 e0_ = *r0_, e1_ = *r1_; \
        E0_##q = pack_f16(__expf(e0_.x) * 0.0078125f, __expf(e1_.x) * 0.0078125f); \
        E1_##q = pack_f16(__expf(e0_.y) * 0.0078125f, __expf(e1_.y) * 0.0078125f); }
    FOR_Q(INIT_E)
#undef INIT_E

    const float trS0 = transfer[j0 * L_DIM + stop];
    const float trS1 = transfer[(j0 | 1) * L_DIM + stop];

    // ---- init: u = exp(f_1 + tr[start] + f_2) ----
    {
        float2 f1v = f2[1 * 64 + p];
        float2 f2v = f2[2 * 64 + p];
        const float2* ts = reinterpret_cast<const float2*>(transfer + start * L_DIM + j0);
        float2 tsv = *ts;
        LdsU[0][p] = __builtin_bit_cast(unsigned int,
                        pack_f16(__expf(f1v.x + f2v.x + tsv.x),
                                 __expf(f1v.y + f2v.y + tsv.y)));
    }
    float2 fa = f2[3 * 64 + p];   // f_{t+1} consumed at t=2
    float2 fb = f2[4 * 64 + p];
    float S = 0.f;

    int cur = 0;
    float accF0 = 0.f, accF1 = 0.f;

// one uint4 (4 u-dwords) against 4 E pairs, both labels
#define DOT4(V, Q0, Q1, Q2, Q3) \
    a0 = fdot2_acc(uint_as_h2(V.x), E0_##Q0, a0); \
    c0 = fdot2_acc(uint_as_h2(V.x), E1_##Q0, c0); \
    a1 = fdot2_acc(uint_as_h2(V.y), E0_##Q1, a1); \
    c1 = fdot2_acc(uint_as_h2(V.y), E1_##Q1, c1); \
    a2 = fdot2_acc(uint_as_h2(V.z), E0_##Q2, a2); \
    c2 = fdot2_acc(uint_as_h2(V.z), E1_##Q2, c2); \
    a3 = fdot2_acc(uint_as_h2(V.w), E0_##Q3, a3); \
    c3 = fdot2_acc(uint_as_h2(V.w), E1_##Q3, c3);

    for (int t = 2; t <= T_DIM - 1; ++t) {
        int tp = t + 3; if (tp > T_DIM - 1) tp = T_DIM - 1;
        float2 fnew = f2[tp * 64 + p];        // stays in flight (no vmcnt drain)
        float fe0 = __expf(fa.x);
        float fe1 = __expf(fa.y);

        // prior-iteration ds_write must be visible before this read
        asm volatile("s_waitcnt lgkmcnt(0)" ::: "memory");
        const uint4* P4 = reinterpret_cast<const uint4*>(&LdsU[cur][0]);

        float a0 = 0.f, a1 = 0.f, a2 = 0.f, a3 = 0.f;
        float c0 = 0.f, c1 = 0.f, c2 = 0.f, c3 = 0.f;

        {   // group 0: q 0..15
            uint4 va = P4[0], vb = P4[1], vc = P4[2], vd = P4[3];
            if ((t & 15) == 0) {              // renorm: u0 free from broadcast
                float u0 = (float)uint_as_h2(va.x).x;
                float rr = __builtin_amdgcn_rcpf(u0);
                S += __logf(u0);
                fe0 *= rr; fe1 *= rr;
            }
            DOT4(va, 0, 1, 2, 3)
            DOT4(vb, 4, 5, 6, 7)
            DOT4(vc, 8, 9, 10, 11)
            DOT4(vd, 12, 13, 14, 15)
        }
        asm volatile("" ::: "memory");        // fence: cap live u at 16 dwords
        {   // group 1: q 16..31
            uint4 va = P4[4], vb = P4[5], vc = P4[6], vd = P4[7];
            DOT4(va, 16, 17, 18, 19)
            DOT4(vb, 20, 21, 22, 23)
            DOT4(vc, 24, 25, 26, 27)
            DOT4(vd, 28, 29, 30, 31)
        }
        asm volatile("" ::: "memory");
        {   // group 2: q 32..47
            uint4 va = P4[8], vb = P4[9], vc = P4[10], vd = P4[11];
            DOT4(va, 32, 33, 34, 35)
            DOT4(vb, 36, 37, 38, 39)
            DOT4(vc, 40, 41, 42, 43)
            DOT4(vd, 44, 45, 46, 47)
        }
        asm volatile("" ::: "memory");
        {   // group 3: q 48..63
            uint4 va = P4[12], vb = P4[13], vc = P4[14], vd = P4[15];
            DOT4(va, 48, 49, 50, 51)
            DOT4(vb, 52, 53, 54, 55)
            DOT4(vc, 56, 57, 58, 59)
            DOT4(vd, 60, 61, 62, 63)
        }

        float acc0 = (a0 + a1) + (a2 + a3);
        float acc1 = (c0 + c1) + (c2 + c3);

        if (t < T_DIM - 1) {
            float un0 = acc0 * fe0;
            float un1 = acc1 * fe1;
            fa = fb; fb = fnew;
            LdsU[cur ^ 1][p] = __builtin_bit_cast(unsigned int, pack_f16(un0, un1));
            cur ^= 1;
        } else {
            accF0 = acc0; accF1 = acc1;
        }
    }
#undef DOT4

    S += 510.0f * LOG128;   // folded 1/128 per dot

    // ---- sentence_score = LSE over 128 j (2 per lane) ----
    float x0 = __logf(accF0) + S + trS0;
    float x1 = __logf(accF1) + S + trS1;
    float mx = fmaxf(x0, x1);
#pragma unroll
    for (int d = 1; d < 64; d <<= 1) mx = fmaxf(mx, __shfl_xor(mx, d));
    float ex = __expf(x0 - mx) + __expf(x1 - mx);
#pragma unroll
    for (int d = 1; d < 64; d <<= 1) ex += __shfl_xor(ex, d);
    float sentence = mx + __logf(ex);

    // ---- gold score: 511 terms over 64 lanes ----
    float es = 0.f, ts = 0.f;
#pragma unroll
    for (int k = 0; k < 8; ++k) {
        int t = 1 + lane + (k << 6);
        if (t < T_DIM) {
            int tg = target[b * T_DIM + t];
            es += fbase[t * L_DIM + tg];
            int pr = (t == 1) ? start : target[b * T_DIM + t - 1];
            ts += transfer[pr * L_DIM + tg];
        }
    }
#pragma unroll
    for (int d = 1; d < 64; d <<= 1) {
        es += __shfl_xor(es, d);
        ts += __shfl_xor(ts, d);
    }

    if (lane == 0) {
        float emit0 = fbase[start];          // feats[b, 0, start]
        out[b] = sentence - __expf(emit0 + es + ts);
    }
}

extern "C" void kernel_launch(void* const* d_in, const int* in_sizes, int n_in,
                              void* d_out, int out_size, void* d_ws, size_t ws_size,
                              hipStream_t stream) {
    const float* feats    = (const float*)d_in[0];
    const float* transfer = (const float*)d_in[1];
    const int*   target   = (const int*)d_in[2];
    const int*   startp   = (const int*)d_in[3];
    const int*   stopp    = (const int*)d_in[4];
    float* outp = (float*)d_out;
    int B = in_sizes[0] / (T_DIM * L_DIM);
    hipLaunchKernelGGL(crf_fwd_kernel, dim3(B), dim3(64), 0, stream,
                       feats, transfer, target, startp, stopp, outp);
}